// Round 1
// baseline (444.920 us; speedup 1.0000x reference)
//
#include <hip/hip_runtime.h>
#include <hip/hip_bf16.h>
#include <math.h>

#define E 4
#define B 8192
#define F 2048
#define L 100
#define NROWS (E * B)          // 32768
#define LAMBDA 1.0f

typedef __attribute__((ext_vector_type(8))) short bf16x8;
typedef __attribute__((ext_vector_type(4))) float f32x4;

static __device__ inline unsigned short f2bf(float x) {
    unsigned u = __float_as_uint(x);
    unsigned r = (u + 0x7FFFu + ((u >> 16) & 1u)) >> 16;   // RNE
    return (unsigned short)r;
}

// ---- sums geometry ----
#define SG 4
#define NSG 25                 // 25 * 4 = 100 labels
#define SBS 8
#define SRW (B / SBS)          // 1024 rows per slice
#define NSUM (E * SBS * NSG)   // 800 units

// ---- gemm geometry ----
#define GBM 128                // feats rows per unit (N-dim)
#define GNC 112                // logit cols padded 100->112 (M-dim, 7 tiles)
#define GKC 64
#define APAD 72
#define NGEMM (NROWS / GBM)    // 256 units
#define NUNIT (NGEMM + NSUM)   // 1056 work units
#define KMB 512                // persistent blocks (2/CU co-resident)

// --------- K1: W[2048][100] f32 -> Wt[112][2048] bf16 (transposed+pad) ------
// Coalesced LDS-transpose version; also folds all zero-init (was 2 memsets).
__global__ void __launch_bounds__(256) k_prep(const float* __restrict__ W,
                                              unsigned short* __restrict__ Wt,
                                              float* __restrict__ ce_accum,
                                              int* __restrict__ counts,
                                              int* __restrict__ ctr) {
    __shared__ float st[64][101];            // 101 pad: 2-way LDS aliasing (free)
    int t = threadIdx.x;
    int b = blockIdx.x;                      // 32 blocks, 64 k-rows each
    if (b == 0) {
        for (int i = t; i < E * L; i += 256) counts[i] = 0;
        if (t == 0) { ce_accum[0] = 0.f; ctr[0] = 0; }
    }
    int k0 = b * 64;
    // linear coalesced read: W[(k0+r)*L + c] == W[k0*L + i] for i = r*100+c
    for (int i = t; i < 64 * 100; i += 256) {
        st[i / 100][i % 100] = W[(size_t)k0 * L + i];
    }
    __syncthreads();
    // write Wt[n][k0..k0+64): 112 rows * 32 uint (2 bf16 each), coalesced per row
    for (int i = t; i < 112 * 32; i += 256) {
        int n = i >> 5, kp = i & 31;
        unsigned lo = 0, hi = 0;
        if (n < L) {
            lo = f2bf(st[kp * 2][n]);
            hi = f2bf(st[kp * 2 + 1][n]);
        }
        *(unsigned*)&Wt[(size_t)n * F + k0 + kp * 2] = lo | (hi << 16);
    }
}

// round-half-up pack of two f32 -> packed bf16x2 (hi<<16 | lo)
static __device__ inline unsigned pack_bf(float lo, float hi) {
    unsigned ul = __float_as_uint(lo) + 0x8000u;
    unsigned uh = __float_as_uint(hi) + 0x8000u;
    return __builtin_amdgcn_perm(uh, ul, 0x07060302u);
}

// ---- K2: persistent work-steal kernel. Units [0,256) = MFMA gemm+CE over
// 128 rows; units [256,1056) = tagged-stream label sums over (env,slice,grp).
__global__ void __launch_bounds__(512, 4) k_main(const float* __restrict__ feats,
                                                 const int* __restrict__ y,
                                                 const unsigned short* __restrict__ Wt,
                                                 const float* __restrict__ bias,
                                                 float* __restrict__ partial,
                                                 int* __restrict__ counts,
                                                 float* __restrict__ ce_accum,
                                                 int* __restrict__ ctr) {
    __shared__ __align__(16) char sm[34624];
    __shared__ int s_unit;
    int t = threadIdx.x;

    for (;;) {
        __syncthreads();                       // protect LDS reuse across units
        if (t == 0) s_unit = atomicAdd(ctr, 1);
        __syncthreads();
        int u = s_unit;
        if (u >= NUNIT) break;                 // uniform across block

        if (u < NGEMM) {
            // ================= GEMM + CE =================
            unsigned short* As = (unsigned short*)sm;            // 128*72*2 = 18432
            unsigned short* Ws = As + GBM * APAD;                // 112*72*2 = 16128
            float* red = (float*)(sm + 34560);                   // 8 floats
            int wave = t >> 6, lane = t & 63;
            int quad = lane >> 4, l16 = lane & 15;
            size_t row0 = (size_t)u * GBM;

            f32x4 acc[7];
#pragma unroll
            for (int ct = 0; ct < 7; ++ct) acc[ct] = (f32x4){0.f, 0.f, 0.f, 0.f};

            int srow = t >> 2;   // 0..127
            int sq = t & 3;      // 16-elem quarter of the 64-k chunk

            const float* aptr = feats + (row0 + srow) * (size_t)F + sq * 16;
            const unsigned short* wptr = Wt + (size_t)srow * F + sq * 16;

            float4 pa[4];
            uint4 pw[2];
#pragma unroll
            for (int i = 0; i < 4; ++i) pa[i] = ((const float4*)aptr)[i];
            if (srow < GNC) {
#pragma unroll
                for (int i = 0; i < 2; ++i) pw[i] = ((const uint4*)wptr)[i];
            }

            for (int k0 = 0; k0 < F; k0 += GKC) {
                // stage prefetched regs -> LDS (A: f32 -> bf16 via add+v_perm)
                unsigned uu[8];
#pragma unroll
                for (int i = 0; i < 4; ++i) {
                    uu[i * 2]     = pack_bf(pa[i].x, pa[i].y);
                    uu[i * 2 + 1] = pack_bf(pa[i].z, pa[i].w);
                }
                *(uint4*)&As[srow * APAD + sq * 16]     = make_uint4(uu[0], uu[1], uu[2], uu[3]);
                *(uint4*)&As[srow * APAD + sq * 16 + 8] = make_uint4(uu[4], uu[5], uu[6], uu[7]);
                if (srow < GNC) {
                    *(uint4*)&Ws[srow * APAD + sq * 16] = pw[0];
                    *(uint4*)&Ws[srow * APAD + sq * 16 + 8] = pw[1];
                }
                __syncthreads();

                if (k0 + GKC < F) {
                    const float* ap = aptr + k0 + GKC;
                    const unsigned short* wp = wptr + k0 + GKC;
#pragma unroll
                    for (int i = 0; i < 4; ++i) pa[i] = ((const float4*)ap)[i];
                    if (srow < GNC) {
#pragma unroll
                        for (int i = 0; i < 2; ++i) pw[i] = ((const uint4*)wp)[i];
                    }
                }

#pragma unroll
                for (int ks = 0; ks < 2; ++ks) {
                    bf16x8 bfr = *(const bf16x8*)&As[(wave * 16 + l16) * APAD + ks * 32 + quad * 8];
#pragma unroll
                    for (int ct = 0; ct < 7; ++ct) {
                        bf16x8 af = *(const bf16x8*)&Ws[(ct * 16 + l16) * APAD + ks * 32 + quad * 8];
                        acc[ct] = __builtin_amdgcn_mfma_f32_16x16x32_bf16(af, bfr, acc[ct], 0, 0, 0);
                    }
                }
                __syncthreads();
            }

            // fused softmax-CE epilogue (D: lane&15 = row, col = 16*ct+quad*4+r)
            int grow = (int)row0 + wave * 16 + l16;
            int lab = y[grow];
            float vv[7][4];
            float vm = -1e30f;
#pragma unroll
            for (int ct = 0; ct < 7; ++ct) {
#pragma unroll
                for (int r = 0; r < 4; ++r) {
                    int c = ct * 16 + quad * 4 + r;
                    float bb = (c < L) ? bias[c] : 0.f;
                    float v = acc[ct][r] + bb;
                    vv[ct][r] = v;
                    if (c < L) vm = fmaxf(vm, v);
                }
            }
            vm = fmaxf(vm, __shfl_xor(vm, 16));
            vm = fmaxf(vm, __shfl_xor(vm, 32));
            float se = 0.f, tv = 0.f;
#pragma unroll
            for (int ct = 0; ct < 7; ++ct) {
#pragma unroll
                for (int r = 0; r < 4; ++r) {
                    int c = ct * 16 + quad * 4 + r;
                    if (c < L) se += __expf(vv[ct][r] - vm);
                    if (c == lab) tv = vv[ct][r];
                }
            }
            se += __shfl_xor(se, 16);
            se += __shfl_xor(se, 32);
            tv += __shfl_xor(tv, 16);
            tv += __shfl_xor(tv, 32);
            float ce = vm + __logf(se) - tv;
#pragma unroll
            for (int s = 1; s <= 8; s <<= 1) ce += __shfl_xor(ce, s);
            if (lane == 0) red[wave] = ce;
            __syncthreads();
            if (t == 0) {
                float v = 0.f;
#pragma unroll
                for (int w = 0; w < 8; ++w) v += red[w];
                atomicAdd(ce_accum, v);
            }
        } else {
            // ================= tagged-stream label sums =================
            int* ys = (int*)sm;                                   // 4096 B
            unsigned short* list = (unsigned short*)(sm + 4096);  // 2048 B
            int* cnt4 = (int*)(sm + 4096 + 2048);                 // 16 B
            int* ntot = (int*)(sm + 4096 + 2048 + 16);            // 4 B
            int bi = u - NGEMM;
            int lg = bi % NSG;
            int bs = (bi / NSG) % SBS;
            int e  = bi / (NSG * SBS);
            int lab0 = lg * SG;

            if (t < SG) cnt4[t] = 0;
            if (t == 8) ntot[0] = 0;
            const int* yb = y + e * B + bs * SRW;
            ys[t] = yb[t];
            ys[t + 512] = yb[t + 512];
            __syncthreads();

            for (int r = t; r < SRW; r += 512) {
                int lb = ys[r] - lab0;
                if ((unsigned)lb < SG) {
                    atomicAdd(&cnt4[lb], 1);
                    int p = atomicAdd(ntot, 1);
                    list[p] = (unsigned short)(r | (lb << 10));
                }
            }
            __syncthreads();
            int n = ntot[0];
            int npad = (n + 3) & ~3;
            if (t < npad - n) list[n + t] = 0;   // pad rows (guarded out below)
            __syncthreads();

            const float* fb = feats + ((size_t)e * B + (size_t)bs * SRW) * F + t * 4;
            float4 a0 = make_float4(0.f, 0.f, 0.f, 0.f);
            float4 a1 = a0, a2 = a0, a3 = a0;

            float4 x[4];
            int tg[4];
            if (n > 0) {
#pragma unroll
                for (int j = 0; j < 4; ++j) {
                    int ev = list[j];
                    tg[j] = ev >> 10;
                    x[j] = *(const float4*)(fb + (size_t)(ev & 1023) * F);
                }
                for (int i = 0; i < npad; i += 4) {
                    float4 nx[4];
                    int ntg[4];
                    if (i + 4 < npad) {
#pragma unroll
                        for (int j = 0; j < 4; ++j) {
                            int ev = list[i + 4 + j];
                            ntg[j] = ev >> 10;
                            nx[j] = *(const float4*)(fb + (size_t)(ev & 1023) * F);
                        }
                    }
#pragma unroll
                    for (int j = 0; j < 4; ++j) {
                        if (i + j < n) {   // uniform across block
                            float4 v = x[j];
                            int g = tg[j];  // uniform across block
                            if (g == 0)      { a0.x += v.x; a0.y += v.y; a0.z += v.z; a0.w += v.w; }
                            else if (g == 1) { a1.x += v.x; a1.y += v.y; a1.z += v.z; a1.w += v.w; }
                            else if (g == 2) { a2.x += v.x; a2.y += v.y; a2.z += v.z; a2.w += v.w; }
                            else             { a3.x += v.x; a3.y += v.y; a3.z += v.z; a3.w += v.w; }
                        }
                    }
#pragma unroll
                    for (int j = 0; j < 4; ++j) { x[j] = nx[j]; tg[j] = ntg[j]; }
                }
            }

            float* pb = partial + (((size_t)e * SBS + bs) * L + lab0) * F + t * 4;
            *(float4*)(pb + 0 * F) = a0;   // unconditional: partial is poisoned
            *(float4*)(pb + 1 * F) = a1;
            *(float4*)(pb + 2 * F) = a2;
            *(float4*)(pb + 3 * F) = a3;
            if (t < SG) atomicAdd(&counts[e * L + lab0 + t], cnt4[t]);
        }
    }
}

// -------- K3: partial[e][bs][l][f] -> per-(e,l) variance over feature dim ---
__global__ void __launch_bounds__(512) k_var(const float* __restrict__ partial,
                                             const int* __restrict__ counts,
                                             float* __restrict__ var_out) {
    int el = blockIdx.x;  // e*L + l
    int e = el / L, l = el % L;
    int t = threadIdx.x;
    float inv = 1.f / fmaxf((float)counts[el], 1.f);
    // 512 threads * float4 = 2048 features in one pass; 8 slice streams
    float4 s = make_float4(0.f, 0.f, 0.f, 0.f);
#pragma unroll
    for (int bs = 0; bs < SBS; ++bs) {
        float4 v = *(const float4*)&partial[(((size_t)e * SBS + bs) * L + l) * F + t * 4];
        s.x += v.x; s.y += v.y; s.z += v.z; s.w += v.w;
    }
    float mx = s.x * inv, my = s.y * inv, mz = s.z * inv, mw = s.w * inv;
    float sm = mx + my + mz + mw;
    float sm2 = mx * mx + my * my + mz * mz + mw * mw;
#pragma unroll
    for (int sft = 1; sft <= 32; sft <<= 1) {
        sm += __shfl_xor(sm, sft);
        sm2 += __shfl_xor(sm2, sft);
    }
    __shared__ float r1[8], r2[8];
    int wv = t >> 6, ln = t & 63;
    if (ln == 0) { r1[wv] = sm; r2[wv] = sm2; }
    __syncthreads();
    if (t == 0) {
        float S = 0.f, S2 = 0.f;
#pragma unroll
        for (int w = 0; w < 8; ++w) { S += r1[w]; S2 += r2[w]; }
        var_out[el] = (S2 - S * S / (float)F) / (float)(F - 1);
    }
}

// ------------------------- K4: final scalar combine -------------------------
__global__ void k_final(const int* __restrict__ counts,
                        const float* __restrict__ var_in,
                        const float* __restrict__ ce_accum,
                        float* __restrict__ out) {
    __shared__ float s_sum[128], s_cnt[128];
    int t = threadIdx.x;
    float selsum = 0.f, selcnt = 0.f;
    for (int l = t; l < L; l += 128) {
        float nvis = 0.f, vsum = 0.f;
        for (int e = 0; e < E; ++e) {
            if (counts[e * L + l] > 0) { nvis += 1.f; vsum += var_in[e * L + l]; }
        }
        float per_label = vsum / fmaxf(nvis, 1.f);
        if (nvis > 1.5f) { selsum += per_label; selcnt += 1.f; }
    }
    s_sum[t] = selsum; s_cnt[t] = selcnt;
    __syncthreads();
    for (int s = 64; s > 0; s >>= 1) {
        if (t < s) { s_sum[t] += s_sum[t + s]; s_cnt[t] += s_cnt[t + s]; }
        __syncthreads();
    }
    if (t == 0) {
        float mean_loss = LAMBDA * s_sum[0] / fmaxf(s_cnt[0], 1.f);
        float ce = ce_accum[0] / (float)NROWS;
        out[0] = mean_loss + ce;
    }
}

extern "C" void kernel_launch(void* const* d_in, const int* in_sizes, int n_in,
                              void* d_out, int out_size, void* d_ws, size_t ws_size,
                              hipStream_t stream) {
    const float* feats = (const float*)d_in[0];
    const int*   y     = (const int*)d_in[1];
    const float* Wm    = (const float*)d_in[2];
    const float* bias  = (const float*)d_in[3];
    float* out = (float*)d_out;

    char* ws = (char*)d_ws;
    float*          ce_accum = (float*)ws;                  // 4 B
    int*            ctr      = (int*)(ws + 64);             // 4 B (work-steal)
    int*            counts   = (int*)(ws + 256);            // 1600 B
    float*          var_buf  = (float*)(ws + 2048);         // 1600 B
    float*          partial  = (float*)(ws + 4096);         // E*SBS*L*F*4 = 26.2 MB
    unsigned short* Wt       = (unsigned short*)(ws + 4096 + (size_t)E * SBS * L * F * 4); // 458 KB

    k_prep<<<F / 64, 256, 0, stream>>>(Wm, Wt, ce_accum, counts, ctr);
    k_main<<<KMB, 512, 0, stream>>>(feats, y, Wt, bias, partial, counts, ce_accum, ctr);
    k_var<<<E * L, 512, 0, stream>>>(partial, counts, var_buf);
    k_final<<<1, 128, 0, stream>>>(counts, var_buf, ce_accum, out);
}